// Round 7
// baseline (119.787 us; speedup 1.0000x reference)
//
#include <hip/hip_runtime.h>
#include <math.h>

// B=8, C=64, H=W=64, O=64, K=3, KK=9, HW=4096
// Fully fused formulation, mfma_f32_16x16x32_bf16 (bf16 in, fp32 acc).
// One wave owns 16 pixels (one h-row segment): om conv (K=1152) ->
// wave-private transpose -> deformable conv (K=576). No cross-wave deps.
// Operand orientation (HW-validated rounds 4-6):
//   A = weights:  lane(l16,lq) holds W[m = tile*16+l16][k = step*32+lq*8+j]
//   B = samples:  lane(l16,lq) holds S[k = step*32+lq*8+j][n = px(l16)]
//   C/D: col(=px) = lane&15, row(=m) = (lane>>4)*4 + reg
//
// ws layout (shorts):
//   [0,     36864)  wd_pk : Wd A-frag-packed, idx=((s*4+lq)*64+o)*8+j,
//                   s=t*2+qh (18), k=t*64+qh*32+lq*8+j -> weight[o][c][t]
//   [36864, 73728)  wo_pk : Wo A-frag-packed, idx=((s*4+lq)*32+oc)*8+j,
//                   s=quarter*9+t (36), cg=quarter*32+lq*8+j; oc>=27 -> 0
//   [73728, 73728+4194304)  catT bf16[b][hw][128] (feat c0..63, deg c64..127)
#define WO_PK_OFF 36864
#define CATT_OFF  73728

typedef short  short8  __attribute__((ext_vector_type(8)));
typedef float  float4v __attribute__((ext_vector_type(4)));

static __device__ __forceinline__ short f2bf(float f) {
    unsigned int u = __builtin_bit_cast(unsigned int, f);
    u += 0x7FFFu + ((u >> 16) & 1u);   // round-to-nearest-even
    return (short)(u >> 16);
}
static __device__ __forceinline__ float bf2f(unsigned short u) {
    return __builtin_bit_cast(float, (unsigned int)u << 16);
}

// Merged: blocks [0,512) transpose NCHW fp32 -> catT[b][hw][128] bf16;
// blocks [512,800) pack the two weight tensors into MFMA A-frag layout.
__global__ __launch_bounds__(256) void prep_transpose(
    const float* __restrict__ feat, const float* __restrict__ deg,
    const float* __restrict__ weight, const float* __restrict__ om_weight,
    unsigned short* __restrict__ catT,
    short* __restrict__ wd_pk, short* __restrict__ wo_pk)
{
    __shared__ unsigned short T[64 * 136];     // 17,408 B (transpose role)
    const int tid = threadIdx.x;
    if (blockIdx.x < 512) {
        const int b = blockIdx.x >> 6, h = blockIdx.x & 63;
        const int lane = tid & 63, wv = tid >> 6;
#pragma unroll
        for (int cc = 0; cc < 32; cc++) {
            int c = wv * 32 + cc;              // wave-uniform
            const float* src = (c < 64)
                ? (feat + (size_t)(b * 64 + c) * 4096)
                : (deg  + (size_t)(b * 64 + (c - 64)) * 4096);
            T[lane * 136 + c] = (unsigned short)f2bf(src[h * 64 + lane]);
        }
        __syncthreads();
        const int px = tid >> 2, seg = tid & 3;
        unsigned short* dst =
            catT + (size_t)(b * 4096 + h * 64 + px) * 128 + seg * 32;
#pragma unroll
        for (int j = 0; j < 4; j++)
            *(uint4*)(dst + j * 8) = *(const uint4*)&T[px * 136 + seg * 32 + j * 8];
    } else {
        int idx = (blockIdx.x - 512) * 256 + tid;   // covers exactly 73728
        if (idx < 36864) {
            int j = idx & 7, o = (idx >> 3) & 63;
            int lq = (idx >> 9) & 3, ks = idx >> 11;
            int t = ks >> 1, c = (ks & 1) * 32 + lq * 8 + j;
            wd_pk[idx] = f2bf(weight[(o * 64 + c) * 9 + t]);
        } else {
            int e = idx - 36864;
            int j = e & 7, oc = (e >> 3) & 31;
            int lq = (e >> 8) & 3, ks2 = e >> 10;
            int quarter = ks2 / 9, t = ks2 - quarter * 9;
            int cg = quarter * 32 + lq * 8 + j;
            wo_pk[e] = (oc < 27) ? f2bf(om_weight[(oc * 128 + cg) * 9 + t])
                                 : (short)0;
        }
    }
}

// Fused kernel, software-pipelined. __launch_bounds__(256,2): grid pins
// occupancy at 2 waves/SIMD anyway, so allow up to 256 VGPRs for in-flight
// loads (round-6 codegen used only 80 VGPRs -> ~nothing in flight -> the
// 72 scattered corner loads serialized at full latency).
__global__ __launch_bounds__(256, 2) void fused_kernel(
    const unsigned short* __restrict__ catT, const short* __restrict__ wd_pk,
    const short* __restrict__ wo_pk, const float* __restrict__ om_bias,
    float* __restrict__ out)
{
    __shared__ float T[4 * 576];               // 9,216 B (per-wave 16x36)
    const int tid = threadIdx.x;
    const int lane = tid & 63, wv = tid >> 6;
    const int l16 = lane & 15, lq = lane >> 4;
    const int gw = blockIdx.x * 4 + wv;
    const int b = gw >> 8, tile = gw & 255;
    const int h = tile >> 2, w0 = (tile & 3) << 4;
    const int pxx = w0 + l16;
    const unsigned short* cb = catT + (size_t)b * 4096 * 128;
    const short8 zf = {0, 0, 0, 0, 0, 0, 0, 0};

    // ---------------- phase 1: om conv (pipelined) ----------------
    auto loadB1 = [&](int s) -> short8 {
        int quarter = s / 9, t = s - quarter * 9;
        int ky = t / 3, kx = t - ky * 3;
        int yy = h - 1 + ky, xx = pxx - 1 + kx;
        bool ok = (yy >= 0) & (yy <= 63) & (xx >= 0) & (xx <= 63);
        int yc = min(max(yy, 0), 63), xc = min(max(xx, 0), 63);
        short8 v = *(const short8*)(cb + (yc * 64 + xc) * 128
                                       + quarter * 32 + lq * 8);
        return ok ? v : zf;
    };
    float4v oacc0 = {0.f, 0.f, 0.f, 0.f};
    float4v oacc1 = {0.f, 0.f, 0.f, 0.f};
    short8 b1 = loadB1(0);
#pragma unroll
    for (int s = 0; s < 36; s++) {
        short8 bn = zf;
        if (s + 1 < 36) bn = loadB1(s + 1);    // prefetch next tap
        const short8* Ap = (const short8*)(wo_pk + (size_t)(s * 4 + lq) * 256);
        oacc0 = __builtin_amdgcn_mfma_f32_16x16x32_bf16(Ap[l16], b1, oacc0, 0, 0, 0);
        oacc1 = __builtin_amdgcn_mfma_f32_16x16x32_bf16(Ap[16 + l16], b1, oacc1, 0, 0, 0);
        b1 = bn;
    }

    // ------- phase 2: wave-private transpose -> omv[27] -------
    float* Tw = T + wv * 576;
#pragma unroll
    for (int r = 0; r < 4; r++) {
        Tw[l16 * 36 + lq * 4 + r]      = oacc0[r];   // oc = lq*4+r
        Tw[l16 * 36 + 16 + lq * 4 + r] = oacc1[r];   // oc = 16+lq*4+r
    }
    __syncthreads();
    float omv[28];
#pragma unroll
    for (int jj = 0; jj < 7; jj++)
        *(float4v*)&omv[jj * 4] = *(const float4v*)&Tw[l16 * 36 + jj * 4];
#pragma unroll
    for (int j = 0; j < 27; j++) omv[j] += om_bias[j];

    // ------- phase 3: deformable conv (precompute + pipeline) -------
    float Wb[9][4];
    int   Ob[9][4];
#pragma unroll
    for (int t = 0; t < 9; t++) {
        const int ky = t / 3, kx = t - ky * 3;
        float dy = omv[2 * t], dx = omv[2 * t + 1];
        float mm = 1.f / (1.f + __expf(-omv[18 + t]));   // sigmoid(mask)
        float yf = (float)(h - 1 + ky) + dy;
        float xf = (float)(pxx - 1 + kx) + dx;
        float fy = floorf(yf), fx = floorf(xf);
        int y0 = (int)fy, x0 = (int)fx;
        float wy = yf - fy, wx = xf - fx;
        bool vy0 = (y0 >= 0) & (y0 < 64);
        bool vy1 = (y0 >= -1) & (y0 < 63);
        bool vx0 = (x0 >= 0) & (x0 < 64);
        bool vx1 = (x0 >= -1) & (x0 < 63);
        float a0 = (1.f - wy) * mm, a1 = wy * mm;
        Wb[t][0] = a0 * (1.f - wx) * (float)(vy0 & vx0);
        Wb[t][1] = a0 * wx         * (float)(vy0 & vx1);
        Wb[t][2] = a1 * (1.f - wx) * (float)(vy1 & vx0);
        Wb[t][3] = a1 * wx         * (float)(vy1 & vx1);
        // taps clamped INDEPENDENTLY: clamp(y0+1), not clamp(y0)+1
        int iy0 = min(max(y0, 0), 63),     ix0 = min(max(x0, 0), 63);
        int iy1 = min(max(y0 + 1, 0), 63), ix1 = min(max(x0 + 1, 0), 63);
        Ob[t][0] = (iy0 * 64 + ix0) * 128;  Ob[t][1] = (iy0 * 64 + ix1) * 128;
        Ob[t][2] = (iy1 * 64 + ix0) * 128;  Ob[t][3] = (iy1 * 64 + ix1) * 128;
    }

    float4v acc[4];
#pragma unroll
    for (int mt = 0; mt < 4; mt++) acc[mt] = (float4v){0.f, 0.f, 0.f, 0.f};

    auto loadC = [&](int s, short8* c) {
        int t = s >> 1, qh = s & 1;
        int cho = qh * 32 + lq * 8;            // feat channels only (<64)
#pragma unroll
        for (int r = 0; r < 4; r++)
            c[r] = *(const short8*)(cb + Ob[t][r] + cho);
    };
    short8 cur[4], nxt[4];
    loadC(0, cur);
#pragma unroll
    for (int s = 0; s < 18; s++) {
        if (s + 1 < 18) loadC(s + 1, nxt);     // prefetch next step's corners
        const int t = s >> 1;
        short8 bfr;
#pragma unroll
        for (int j = 0; j < 8; j++) {
            float v = Wb[t][0] * bf2f((unsigned short)cur[0][j])
                    + Wb[t][1] * bf2f((unsigned short)cur[1][j])
                    + Wb[t][2] * bf2f((unsigned short)cur[2][j])
                    + Wb[t][3] * bf2f((unsigned short)cur[3][j]);
            bfr[j] = f2bf(v);
        }
        const short8* Dp = (const short8*)(wd_pk + (size_t)(s * 4 + lq) * 512);
        acc[0] = __builtin_amdgcn_mfma_f32_16x16x32_bf16(Dp[l16],      bfr, acc[0], 0, 0, 0);
        acc[1] = __builtin_amdgcn_mfma_f32_16x16x32_bf16(Dp[16 + l16], bfr, acc[1], 0, 0, 0);
        acc[2] = __builtin_amdgcn_mfma_f32_16x16x32_bf16(Dp[32 + l16], bfr, acc[2], 0, 0, 0);
        acc[3] = __builtin_amdgcn_mfma_f32_16x16x32_bf16(Dp[48 + l16], bfr, acc[3], 0, 0, 0);
#pragma unroll
        for (int r = 0; r < 4; r++) cur[r] = nxt[r];
    }

    // store: o = mt*16 + lq*4 + r, px = w0 + l16
    float* ob = out + (size_t)(b * 64) * 4096 + h * 64 + w0 + l16;
#pragma unroll
    for (int mt = 0; mt < 4; mt++)
#pragma unroll
        for (int r = 0; r < 4; r++)
            ob[(mt * 16 + lq * 4 + r) * 4096] = acc[mt][r];
}

extern "C" void kernel_launch(void* const* d_in, const int* in_sizes, int n_in,
                              void* d_out, int out_size, void* d_ws, size_t ws_size,
                              hipStream_t stream)
{
    const float* feat      = (const float*)d_in[0];
    const float* deg       = (const float*)d_in[1];
    const float* weight    = (const float*)d_in[2];
    const float* om_weight = (const float*)d_in[3];
    const float* om_bias   = (const float*)d_in[4];
    float* out = (float*)d_out;
    short* wss = (short*)d_ws;
    unsigned short* catT = (unsigned short*)(wss + CATT_OFF);

    hipLaunchKernelGGL(prep_transpose, dim3(800), dim3(256), 0, stream,
                       feat, deg, weight, om_weight, catT,
                       wss, wss + WO_PK_OFF);
    hipLaunchKernelGGL(fused_kernel,   dim3(512), dim3(256), 0, stream,
                       catT, wss, wss + WO_PK_OFF, om_bias, out);
}